// Round 9
// baseline (404.376 us; speedup 1.0000x reference)
//
#include <hip/hip_runtime.h>
#include <hip/hip_bf16.h>

constexpr int S_ = 4096;
constexpr int D_ = 512;

using f32x4 = __attribute__((ext_vector_type(4))) float;
using s16x4 = __attribute__((ext_vector_type(4))) short;
using s16x8 = __attribute__((ext_vector_type(8))) short;
using u16x4 = __attribute__((ext_vector_type(4))) unsigned short;
using u16x8 = __attribute__((ext_vector_type(8))) unsigned short;

__device__ __forceinline__ unsigned short f2bf(float f) {
    union { float f; unsigned u; } v; v.f = f;
    unsigned r = v.u + 0x7FFFu + ((v.u >> 16) & 1u);
    return (unsigned short)(r >> 16);
}

__device__ __forceinline__ float bf2f(unsigned short u) {
    union { unsigned u; float f; } v; v.u = (unsigned)u << 16; return v.f;
}

__device__ __forceinline__ unsigned pack_bf16(float lo, float hi) {
    float2 t; t.x = lo; t.y = hi;
    __hip_bfloat162 b = __float22bfloat162_rn(t);
    union { __hip_bfloat162 b; unsigned u; } cv; cv.b = b; return cv.u;
}

// 16x16x16 bf16 MFMA via inline asm (no builtin exposed on gfx950; verified r5-r8).
__device__ __forceinline__ f32x4 mfma16(s16x4 a, s16x4 b, f32x4 c) {
    asm volatile("v_mfma_f32_16x16x16_bf16 %0, %1, %2, %0" : "+v"(c) : "v"(a), "v"(b));
    return c;
}

// Y[M=4096][N=512] = (X[M][512] @ W[N][512]^T) * scale
// OUT_MODE: 0 = bf16 row-major, 1 = bf16 transposed ([N][S_]), 2 = fp32 row-major
template<bool IN_BF16, int OUT_MODE>
__global__ __launch_bounds__(256) void proj_kernel(const void* __restrict__ Xv,
                                                   const float* __restrict__ W,
                                                   void* __restrict__ Yv, float scale) {
    constexpr int BM = 128, BN = 64, BK = 64;
    __shared__ unsigned short Xs[BM][BK + 8];
    __shared__ unsigned short Ws_[BN][BK + 8];
    const int m0 = blockIdx.x * BM;
    const int n0 = blockIdx.y * BN;
    const int tid = threadIdx.x;
    const int lane = tid & 63, w = tid >> 6;
    const int wi = w >> 1, wj = w & 1;
    const int lr = lane & 15, lg = lane >> 4;

    f32x4 acc[4][2] = {};

    for (int kt = 0; kt < D_ / BK; ++kt) {
        const int k0 = kt * BK;
        __syncthreads();
        if (IN_BF16) {
            const unsigned short* X = (const unsigned short*)Xv;
#pragma unroll
            for (int r = 0; r < 4; ++r) {
                int idx = tid + r * 256;
                int row = idx >> 3, c8 = idx & 7;
                u16x8 vv = *(const u16x8*)(X + (size_t)(m0 + row) * D_ + k0 + c8 * 8);
                *(u16x8*)&Xs[row][c8 * 8] = vv;
            }
        } else {
            const float* X = (const float*)Xv;
#pragma unroll
            for (int r = 0; r < 8; ++r) {
                int idx = tid + r * 256;
                int row = idx >> 4, c4 = idx & 15;
                f32x4 vv = *(const f32x4*)(X + (size_t)(m0 + row) * D_ + k0 + c4 * 4);
                u16x4 o;
#pragma unroll
                for (int t = 0; t < 4; ++t) o[t] = f2bf(vv[t]);
                *(u16x4*)&Xs[row][c4 * 4] = o;
            }
        }
#pragma unroll
        for (int r = 0; r < 4; ++r) {
            int idx = tid + r * 256;
            int row = idx >> 4, c4 = idx & 15;
            f32x4 vv = *(const f32x4*)(W + (size_t)(n0 + row) * D_ + k0 + c4 * 4);
            u16x4 o;
#pragma unroll
            for (int t = 0; t < 4; ++t) o[t] = f2bf(vv[t]);
            *(u16x4*)&Ws_[row][c4 * 4] = o;
        }
        __syncthreads();
#pragma unroll
        for (int ks = 0; ks < 2; ++ks) {
            s16x8 a[4], b[2];
#pragma unroll
            for (int mf = 0; mf < 4; ++mf)
                a[mf] = *(const s16x8*)&Xs[wi * 64 + mf * 16 + lr][ks * 32 + lg * 8];
#pragma unroll
            for (int nf = 0; nf < 2; ++nf)
                b[nf] = *(const s16x8*)&Ws_[wj * 32 + nf * 16 + lr][ks * 32 + lg * 8];
#pragma unroll
            for (int mf = 0; mf < 4; ++mf)
#pragma unroll
                for (int nf = 0; nf < 2; ++nf)
                    acc[mf][nf] = __builtin_amdgcn_mfma_f32_16x16x32_bf16(a[mf], b[nf], acc[mf][nf], 0, 0, 0);
        }
    }

    if (OUT_MODE == 1) {
        __syncthreads();
        unsigned short* T = &Xs[0][0] + w * 2304;   // per-wave [32][72]
#pragma unroll
        for (int mf = 0; mf < 4; ++mf)
#pragma unroll
            for (int nf = 0; nf < 2; ++nf)
#pragma unroll
                for (int r = 0; r < 4; ++r) {
                    int n_loc = nf * 16 + lr;
                    int i_loc = mf * 16 + lg * 4 + r;
                    T[n_loc * 72 + i_loc] = f2bf(acc[mf][nf][r] * scale);
                }
        __syncthreads();
        unsigned short* Y = (unsigned short*)Yv;
#pragma unroll
        for (int rr = 0; rr < 4; ++rr) {
            int chunk = lane + rr * 64;
            int n_loc = chunk >> 3, c8 = chunk & 7;
            u16x8 vv = *(const u16x8*)&T[n_loc * 72 + c8 * 8];
            *(u16x8*)(Y + (size_t)(n0 + wj * 32 + n_loc) * S_ + m0 + wi * 64 + c8 * 8) = vv;
        }
    } else {
#pragma unroll
        for (int mf = 0; mf < 4; ++mf)
#pragma unroll
            for (int nf = 0; nf < 2; ++nf)
#pragma unroll
                for (int r = 0; r < 4; ++r) {
                    int i = m0 + wi * 64 + mf * 16 + lg * 4 + r;
                    int n = n0 + wj * 32 + nf * 16 + lr;
                    float val = acc[mf][nf][r] * scale;
                    if (OUT_MODE == 0) ((unsigned short*)Yv)[(size_t)i * D_ + n] = f2bf(val);
                    else                ((float*)Yv)[(size_t)i * D_ + n] = val;
                }
    }
}

// Attention, head-axis softmax. Block = 4 waves = i-tile of 16 rows.
// Wave w = head-pair {2w,2w+1}, k-slice kb=w*128. j-tile = 64 keys per
// iteration -> ONE barrier per 48 MFMA-equivalents (vs 8 in prior rounds).
// Swapped QK (mfma(K,Q)): lane holds S[j=jf*16+lg*4+r][i=lr]; exp2 lane-local;
// 8-head denominator via slot-dbuf LDS + lgkm-only barrier; P frag feeds
// 16x16x16 PV directly (j=lg*4+e matches B operand exactly).
// XCD swizzle: XCD n == j-chunk n -> 1MB K/V slice resident in its 4MB L2.
__global__ __launch_bounds__(256, 2) void attn_kernel(const unsigned short* __restrict__ Qp,
                                                      const unsigned short* __restrict__ Kp,
                                                      const unsigned short* __restrict__ VpT,
                                                      unsigned short* __restrict__ partial,
                                                      int njc) {
    __shared__ f32x4 den[2][4][4][64];             // [slot][wave][jf][lane] = 32 KB
    const int nblk = gridDim.x;                    // 256 * njc
    const int bid = blockIdx.x;
    const int rank = (bid & 7) * (nblk >> 3) + (bid >> 3);
    const int jc = rank >> 8;                      // rank / 256
    const int i0 = (rank & 255) * 16;
    const int tid = threadIdx.x;
    const int lane = tid & 63, w = tid >> 6;       // w = head-pair
    const int lr = lane & 15, lg = lane >> 4;
    const int kb = w * 128;

    // ---- persistent Q fragments: 16 i-rows x 128 k (this wave's 2 heads) ----
    s16x8 q[4];
#pragma unroll
    for (int kf = 0; kf < 4; ++kf)
        q[kf] = *(const s16x8*)(Qp + (size_t)(i0 + lr) * D_ + kb + kf * 32 + lg * 8);

    f32x4 acc[2][4] = {};                          // [hh][df]

    const int iters = S_ / 64 / njc;
    const int jbase = jc * (S_ / njc);

    for (int t = 0; t < iters; ++t) {
        const int j0 = jbase + t * 64;
        const int slot = t & 1;

        // ---- K fragments: 64 j-rows x 128 k  (16 x 16B loads) ----
        s16x8 kA[4][4];                            // [jf][kf]
#pragma unroll
        for (int jf = 0; jf < 4; ++jf)
#pragma unroll
            for (int kf = 0; kf < 4; ++kf)
                kA[jf][kf] = *(const s16x8*)(Kp + (size_t)(j0 + jf * 16 + lr) * D_ + kb + kf * 32 + lg * 8);

        // ---- V prefetch for jf=0 (8 x 8B loads), in flight through QK ----
        s16x4 va[8], vb[8];                        // [hh*4+df]
#pragma unroll
        for (int hh = 0; hh < 2; ++hh)
#pragma unroll
            for (int df = 0; df < 4; ++df)
                va[hh * 4 + df] = *(const s16x4*)(VpT + (size_t)(kb + hh * 64 + df * 16 + lr) * S_ + j0 + lg * 4);

        // ---- QK^T (swapped): sf[hh][jf] = S[h][j=jf*16+lg*4+r][i=lr] ----
        f32x4 sf[2][4];
        __builtin_amdgcn_s_setprio(1);
#pragma unroll
        for (int hh = 0; hh < 2; ++hh)
#pragma unroll
            for (int jf = 0; jf < 4; ++jf) {
                f32x4 s = {0.f, 0.f, 0.f, 0.f};
                s = __builtin_amdgcn_mfma_f32_16x16x32_bf16(kA[jf][hh * 2 + 0], q[hh * 2 + 0], s, 0, 0, 0);
                s = __builtin_amdgcn_mfma_f32_16x16x32_bf16(kA[jf][hh * 2 + 1], q[hh * 2 + 1], s, 0, 0, 0);
                sf[hh][jf] = s;
            }
        __builtin_amdgcn_s_setprio(0);

        // ---- exp2 (Q pre-scaled by 1/8*log2e) + 2-head partial denominator ----
#pragma unroll
        for (int hh = 0; hh < 2; ++hh)
#pragma unroll
            for (int jf = 0; jf < 4; ++jf)
#pragma unroll
                for (int r = 0; r < 4; ++r)
                    sf[hh][jf][r] = exp2f(sf[hh][jf][r]);
#pragma unroll
        for (int jf = 0; jf < 4; ++jf)
            den[slot][w][jf][lane] = sf[0][jf] + sf[1][jf];

        // lgkm-only barrier: vmem (V prefetch) stays in flight
        asm volatile("s_waitcnt lgkmcnt(0)" ::: "memory");
        __builtin_amdgcn_s_barrier();

        // ---- total denominator over 4 waves (8 heads), then reciprocal ----
        f32x4 dt[4];
#pragma unroll
        for (int jf = 0; jf < 4; ++jf) {
            dt[jf] = den[slot][0][jf][lane];
#pragma unroll
            for (int wp = 1; wp < 4; ++wp)
                dt[jf] += den[slot][wp][jf][lane];
#pragma unroll
            for (int r = 0; r < 4; ++r)
                dt[jf][r] = __builtin_amdgcn_rcpf(dt[jf][r]);
        }

        // ---- normalize + pack: pb[hh][jf] is the 16x16x16 B operand ----
        s16x4 pb[2][4];
#pragma unroll
        for (int hh = 0; hh < 2; ++hh)
#pragma unroll
            for (int jf = 0; jf < 4; ++jf) {
                union { s16x4 v; uint2 u; } pc;
                pc.u.x = pack_bf16(sf[hh][jf][0] * dt[jf][0], sf[hh][jf][1] * dt[jf][1]);
                pc.u.y = pack_bf16(sf[hh][jf][2] * dt[jf][2], sf[hh][jf][3] * dt[jf][3]);
                pb[hh][jf] = pc.v;
            }

        // ---- PV over 4 jf chunks, V prefetched one jf ahead ----
        __builtin_amdgcn_s_setprio(1);
#pragma unroll
        for (int jf = 0; jf < 4; ++jf) {
            s16x4* cur = (jf & 1) ? vb : va;
            s16x4* nxt = (jf & 1) ? va : vb;
            if (jf < 3) {
#pragma unroll
                for (int hh = 0; hh < 2; ++hh)
#pragma unroll
                    for (int df = 0; df < 4; ++df)
                        nxt[hh * 4 + df] = *(const s16x4*)(VpT + (size_t)(kb + hh * 64 + df * 16 + lr) * S_ + j0 + (jf + 1) * 16 + lg * 4);
            }
#pragma unroll
            for (int hh = 0; hh < 2; ++hh)
#pragma unroll
                for (int df = 0; df < 4; ++df)
                    acc[hh][df] = mfma16(cur[hh * 4 + df], pb[hh][jf], acc[hh][df]);
        }
        __builtin_amdgcn_s_setprio(0);
    }

    // ---- store O[i][d] partial, bf16, u16x4 per lane ----
    unsigned short* P = partial + (size_t)jc * S_ * D_;
#pragma unroll
    for (int hh = 0; hh < 2; ++hh)
#pragma unroll
        for (int df = 0; df < 4; ++df) {
            union { u16x4 v; uint2 u; } pc;
            pc.u.x = pack_bf16(acc[hh][df][0], acc[hh][df][1]);
            pc.u.y = pack_bf16(acc[hh][df][2], acc[hh][df][3]);
            *(u16x4*)(P + (size_t)(i0 + lr) * D_ + kb + hh * 64 + df * 16 + lg * 4) = pc.v;
        }
}

// Sum njc bf16 partials -> bf16 ao. Memory-bound streaming sum.
__global__ __launch_bounds__(256) void reduceN_kernel(const unsigned short* __restrict__ partial,
                                                      unsigned short* __restrict__ outp, int njc) {
    size_t base = ((size_t)blockIdx.x * 256 + threadIdx.x) * 8;
    float s[8] = {};
    for (int c = 0; c < njc; ++c) {
        u16x8 vv = *(const u16x8*)(partial + (size_t)c * S_ * D_ + base);
#pragma unroll
        for (int e = 0; e < 8; ++e) s[e] += bf2f(vv[e]);
    }
    u16x8 o;
#pragma unroll
    for (int e = 0; e < 8; ++e) o[e] = f2bf(s[e]);
    *(u16x8*)(outp + base) = o;
}

extern "C" void kernel_launch(void* const* d_in, const int* in_sizes, int n_in,
                              void* d_out, int out_size, void* d_ws, size_t ws_size,
                              hipStream_t stream) {
    const float* q  = (const float*)d_in[0];
    const float* k  = (const float*)d_in[1];
    const float* v  = (const float*)d_in[2];
    const float* Wq = (const float*)d_in[3];
    const float* Wk = (const float*)d_in[4];
    const float* Wv = (const float*)d_in[5];
    const float* Wo = (const float*)d_in[6];

    // ws: 12MB (Qp,Kp,VpT) + njc*4MB (bf16 partial) + 4MB (ao)
    int njc = 2;
    if      (ws_size >= ((size_t)(16 + 4 * 8) << 20)) njc = 8;   // XCD == j-chunk
    else if (ws_size >= ((size_t)(16 + 4 * 4) << 20)) njc = 4;

    char* ws = (char*)d_ws;
    unsigned short* Qp  = (unsigned short*)(ws);                    // 4 MB bf16 [S][D]
    unsigned short* Kp  = (unsigned short*)(ws + (4u  << 20));      // 4 MB bf16 [S][D]
    unsigned short* VpT = (unsigned short*)(ws + (8u  << 20));      // 4 MB bf16 [D][S]
    unsigned short* part= (unsigned short*)(ws + (12u << 20));      // njc * 4 MB bf16 [jc][S][D]
    unsigned short* ao  = (unsigned short*)(ws + ((size_t)(12 + 4 * njc) << 20)); // 4 MB bf16

    const float qscale = 0.125f * 1.44269504088896340736f;  // 1/8 * log2(e)

    dim3 pb(256);
    dim3 pg(S_ / 128, D_ / 64);
    proj_kernel<false, 0><<<pg, pb, 0, stream>>>(q, Wq, Qp, qscale);
    proj_kernel<false, 0><<<pg, pb, 0, stream>>>(k, Wk, Kp, 1.0f);
    proj_kernel<false, 1><<<pg, pb, 0, stream>>>(v, Wv, VpT, 1.0f);
    attn_kernel<<<dim3(256 * njc), pb, 0, stream>>>(Qp, Kp, VpT, part, njc);
    reduceN_kernel<<<dim3(S_ * D_ / 2048), pb, 0, stream>>>(part, ao, njc);
    proj_kernel<true, 2><<<pg, pb, 0, stream>>>(ao, Wo, (float*)d_out, 1.0f);
}

// Round 10
// 247.933 us; speedup vs baseline: 1.6310x; 1.6310x over previous
//
#include <hip/hip_runtime.h>
#include <hip/hip_bf16.h>

constexpr int S_ = 4096;
constexpr int D_ = 512;

using f32x4 = __attribute__((ext_vector_type(4))) float;
using s16x4 = __attribute__((ext_vector_type(4))) short;
using s16x8 = __attribute__((ext_vector_type(8))) short;
using u16x4 = __attribute__((ext_vector_type(4))) unsigned short;
using u16x8 = __attribute__((ext_vector_type(8))) unsigned short;

__device__ __forceinline__ unsigned short f2bf(float f) {
    union { float f; unsigned u; } v; v.f = f;
    unsigned r = v.u + 0x7FFFu + ((v.u >> 16) & 1u);
    return (unsigned short)(r >> 16);
}

__device__ __forceinline__ float bf2f(unsigned short u) {
    union { unsigned u; float f; } v; v.u = (unsigned)u << 16; return v.f;
}

__device__ __forceinline__ unsigned pack_bf16(float lo, float hi) {
    float2 t; t.x = lo; t.y = hi;
    __hip_bfloat162 b = __float22bfloat162_rn(t);
    union { __hip_bfloat162 b; unsigned u; } cv; cv.b = b; return cv.u;
}

// 16x16x16 bf16 MFMA via inline asm (no builtin on gfx950; verified r5-r8).
__device__ __forceinline__ f32x4 mfma16(s16x4 a, s16x4 b, f32x4 c) {
    asm volatile("v_mfma_f32_16x16x16_bf16 %0, %1, %2, %0" : "+v"(c) : "v"(a), "v"(b));
    return c;
}

// Y[M=4096][N=512] = (X[M][512] @ W[N][512]^T) * scale
// OUT_MODE: 0 = bf16 row-major, 1 = bf16 transposed ([N][S_]), 2 = fp32 row-major
template<bool IN_BF16, int OUT_MODE>
__global__ __launch_bounds__(256) void proj_kernel(const void* __restrict__ Xv,
                                                   const float* __restrict__ W,
                                                   void* __restrict__ Yv, float scale) {
    constexpr int BM = 128, BN = 64, BK = 64;
    __shared__ unsigned short Xs[BM][BK + 8];
    __shared__ unsigned short Ws_[BN][BK + 8];
    const int m0 = blockIdx.x * BM;
    const int n0 = blockIdx.y * BN;
    const int tid = threadIdx.x;
    const int lane = tid & 63, w = tid >> 6;
    const int wi = w >> 1, wj = w & 1;
    const int lr = lane & 15, lg = lane >> 4;

    f32x4 acc[4][2] = {};

    for (int kt = 0; kt < D_ / BK; ++kt) {
        const int k0 = kt * BK;
        __syncthreads();
        if (IN_BF16) {
            const unsigned short* X = (const unsigned short*)Xv;
#pragma unroll
            for (int r = 0; r < 4; ++r) {
                int idx = tid + r * 256;
                int row = idx >> 3, c8 = idx & 7;
                u16x8 vv = *(const u16x8*)(X + (size_t)(m0 + row) * D_ + k0 + c8 * 8);
                *(u16x8*)&Xs[row][c8 * 8] = vv;
            }
        } else {
            const float* X = (const float*)Xv;
#pragma unroll
            for (int r = 0; r < 8; ++r) {
                int idx = tid + r * 256;
                int row = idx >> 4, c4 = idx & 15;
                f32x4 vv = *(const f32x4*)(X + (size_t)(m0 + row) * D_ + k0 + c4 * 4);
                u16x4 o;
#pragma unroll
                for (int t = 0; t < 4; ++t) o[t] = f2bf(vv[t]);
                *(u16x4*)&Xs[row][c4 * 4] = o;
            }
        }
#pragma unroll
        for (int r = 0; r < 4; ++r) {
            int idx = tid + r * 256;
            int row = idx >> 4, c4 = idx & 15;
            f32x4 vv = *(const f32x4*)(W + (size_t)(n0 + row) * D_ + k0 + c4 * 4);
            u16x4 o;
#pragma unroll
            for (int t = 0; t < 4; ++t) o[t] = f2bf(vv[t]);
            *(u16x4*)&Ws_[row][c4 * 4] = o;
        }
        __syncthreads();
#pragma unroll
        for (int ks = 0; ks < 2; ++ks) {
            s16x8 a[4], b[2];
#pragma unroll
            for (int mf = 0; mf < 4; ++mf)
                a[mf] = *(const s16x8*)&Xs[wi * 64 + mf * 16 + lr][ks * 32 + lg * 8];
#pragma unroll
            for (int nf = 0; nf < 2; ++nf)
                b[nf] = *(const s16x8*)&Ws_[wj * 32 + nf * 16 + lr][ks * 32 + lg * 8];
#pragma unroll
            for (int mf = 0; mf < 4; ++mf)
#pragma unroll
                for (int nf = 0; nf < 2; ++nf)
                    acc[mf][nf] = __builtin_amdgcn_mfma_f32_16x16x32_bf16(a[mf], b[nf], acc[mf][nf], 0, 0, 0);
        }
    }

    if (OUT_MODE == 1) {
        __syncthreads();
        unsigned short* T = &Xs[0][0] + w * 2304;   // per-wave [32][72]
#pragma unroll
        for (int mf = 0; mf < 4; ++mf)
#pragma unroll
            for (int nf = 0; nf < 2; ++nf)
#pragma unroll
                for (int r = 0; r < 4; ++r) {
                    int n_loc = nf * 16 + lr;
                    int i_loc = mf * 16 + lg * 4 + r;
                    T[n_loc * 72 + i_loc] = f2bf(acc[mf][nf][r] * scale);
                }
        __syncthreads();
        unsigned short* Y = (unsigned short*)Yv;
#pragma unroll
        for (int rr = 0; rr < 4; ++rr) {
            int chunk = lane + rr * 64;
            int n_loc = chunk >> 3, c8 = chunk & 7;
            u16x8 vv = *(const u16x8*)&T[n_loc * 72 + c8 * 8];
            *(u16x8*)(Y + (size_t)(n0 + wj * 32 + n_loc) * S_ + m0 + wi * 64 + c8 * 8) = vv;
        }
    } else {
#pragma unroll
        for (int mf = 0; mf < 4; ++mf)
#pragma unroll
            for (int nf = 0; nf < 2; ++nf)
#pragma unroll
                for (int r = 0; r < 4; ++r) {
                    int i = m0 + wi * 64 + mf * 16 + lg * 4 + r;
                    int n = n0 + wj * 32 + nf * 16 + lr;
                    float val = acc[mf][nf][r] * scale;
                    if (OUT_MODE == 0) ((unsigned short*)Yv)[(size_t)i * D_ + n] = f2bf(val);
                    else                ((float*)Yv)[(size_t)i * D_ + n] = val;
                }
    }
}

// Attention, head-axis softmax — ZERO denominator exchange.
// Block = 4 waves, i-tile 32, Q (32x512) staged in LDS once.
// Per 64-key super-tile:
//  Phase A (j-split): wave w computes j16=w's 16 keys, ALL 8 heads x 32 i
//    (swapped QK mfma(K,Q)) -> softmax fully lane-local (den = sum over the
//    8 head-regs) -> writes NORMALIZED P (packed bf16) to LDS.
//  lgkm-only barrier (global loads stay in flight).
//  Phase B (d-split): wave w owns heads 2w,2w+1; P read from LDS is directly
//    the 16x16x16 PV B-operand; V from global. Second lgkm barrier.
// 2 barriers per 64 keys = 32 MFMA-equiv per barrier (R8 had 6).
__global__ __launch_bounds__(256, 2) void attn_kernel(const unsigned short* __restrict__ Qp,
                                                      const unsigned short* __restrict__ Kp,
                                                      const unsigned short* __restrict__ VpT,
                                                      unsigned short* __restrict__ partial,
                                                      int njc) {
    __shared__ unsigned short Qs[32][520];         // 33.3 KB, +8 pad (4-bank row skew)
    __shared__ unsigned short Ps[8][32][72];       // 36 KB normalized P [h][i][j], +8 pad
    const int nblk = gridDim.x;                    // 128 * njc
    const int bid = blockIdx.x;
    const int rank = (bid & 7) * (nblk >> 3) + (bid >> 3);  // XCD n == j-chunk n (njc=8)
    const int jc = rank >> 7;
    const int i0 = (rank & 127) * 32;
    const int tid = threadIdx.x;
    const int lane = tid & 63, w = tid >> 6;
    const int lr = lane & 15, lg = lane >> 4;

    // ---- stage Q tile 32x512 bf16 ----
#pragma unroll
    for (int r = 0; r < 8; ++r) {
        int idx = tid + r * 256;
        int row = idx >> 6, c8 = idx & 63;
        u16x8 vv = *(const u16x8*)(Qp + (size_t)(i0 + row) * D_ + c8 * 8);
        *(u16x8*)&Qs[row][c8 * 8] = vv;
    }
    __syncthreads();

    f32x4 acc[2][2][4] = {};                       // [hh][mf][df]

    const int nst = S_ / 64 / njc;
    const int jbase = jc * (S_ / njc);

    for (int st = 0; st < nst; ++st) {
        const int j0 = jbase + st * 64;

        // ================= phase A: j16 = w, all 8 heads =================
        const unsigned short* krow = Kp + (size_t)(j0 + w * 16 + lr) * D_ + lg * 8;
        s16x8 kA[2][2];
        kA[0][0] = *(const s16x8*)(krow);
        kA[0][1] = *(const s16x8*)(krow + 32);
        f32x4 sf[8][2];
#pragma unroll
        for (int h = 0; h < 8; ++h) {
            if (h < 7) {                           // prefetch next head's K
                kA[(h + 1) & 1][0] = *(const s16x8*)(krow + (h + 1) * 64);
                kA[(h + 1) & 1][1] = *(const s16x8*)(krow + (h + 1) * 64 + 32);
            }
#pragma unroll
            for (int f = 0; f < 2; ++f) {
                s16x8 b0 = *(const s16x8*)&Qs[f * 16 + lr][h * 64 + lg * 8];
                s16x8 b1 = *(const s16x8*)&Qs[f * 16 + lr][h * 64 + 32 + lg * 8];
                f32x4 s = {0.f, 0.f, 0.f, 0.f};
                s = __builtin_amdgcn_mfma_f32_16x16x32_bf16(kA[h & 1][0], b0, s, 0, 0, 0);
                s = __builtin_amdgcn_mfma_f32_16x16x32_bf16(kA[h & 1][1], b1, s, 0, 0, 0);
                sf[h][f] = s;
            }
        }
        // ---- lane-local softmax over heads (Q pre-scaled by 1/8*log2e) ----
#pragma unroll
        for (int f = 0; f < 2; ++f) {
            f32x4 den = {0.f, 0.f, 0.f, 0.f};
#pragma unroll
            for (int h = 0; h < 8; ++h) {
#pragma unroll
                for (int r = 0; r < 4; ++r)
                    sf[h][f][r] = exp2f(sf[h][f][r]);
                den += sf[h][f];
            }
            f32x4 rd;
#pragma unroll
            for (int r = 0; r < 4; ++r) rd[r] = __builtin_amdgcn_rcpf(den[r]);
#pragma unroll
            for (int h = 0; h < 8; ++h) {
                uint2 pc;
                pc.x = pack_bf16(sf[h][f][0] * rd[0], sf[h][f][1] * rd[1]);
                pc.y = pack_bf16(sf[h][f][2] * rd[2], sf[h][f][3] * rd[3]);
                *(uint2*)&Ps[h][f * 16 + lr][w * 16 + lg * 4] = pc;
            }
        }
        asm volatile("s_waitcnt lgkmcnt(0)" ::: "memory");
        __builtin_amdgcn_s_barrier();

        // ================= phase B: heads 2w,2w+1, 64 keys =================
#pragma unroll
        for (int jf = 0; jf < 4; ++jf) {
            s16x4 vA[2][4];
#pragma unroll
            for (int hh = 0; hh < 2; ++hh)
#pragma unroll
                for (int df = 0; df < 4; ++df)
                    vA[hh][df] = *(const s16x4*)(VpT + (size_t)(w * 128 + hh * 64 + df * 16 + lr) * S_ + j0 + jf * 16 + lg * 4);
#pragma unroll
            for (int hh = 0; hh < 2; ++hh)
#pragma unroll
                for (int mf = 0; mf < 2; ++mf) {
                    s16x4 pa = *(const s16x4*)&Ps[w * 2 + hh][mf * 16 + lr][jf * 16 + lg * 4];
#pragma unroll
                    for (int df = 0; df < 4; ++df)
                        acc[hh][mf][df] = mfma16(vA[hh][df], pa, acc[hh][mf][df]);
                }
        }
        asm volatile("s_waitcnt lgkmcnt(0)" ::: "memory");
        __builtin_amdgcn_s_barrier();
    }

    // ---- store O[i][d] partial, bf16 ----
    unsigned short* P = partial + (size_t)jc * S_ * D_;
#pragma unroll
    for (int hh = 0; hh < 2; ++hh)
#pragma unroll
        for (int mf = 0; mf < 2; ++mf)
#pragma unroll
            for (int df = 0; df < 4; ++df) {
                union { u16x4 v; uint2 u; } pc;
                pc.u.x = pack_bf16(acc[hh][mf][df][0], acc[hh][mf][df][1]);
                pc.u.y = pack_bf16(acc[hh][mf][df][2], acc[hh][mf][df][3]);
                *(u16x4*)(P + (size_t)(i0 + mf * 16 + lr) * D_ + w * 128 + hh * 64 + df * 16 + lg * 4) = pc.v;
            }
}

// Sum njc bf16 partials -> bf16 ao. Memory-bound streaming sum.
__global__ __launch_bounds__(256) void reduceN_kernel(const unsigned short* __restrict__ partial,
                                                      unsigned short* __restrict__ outp, int njc) {
    size_t base = ((size_t)blockIdx.x * 256 + threadIdx.x) * 8;
    float s[8] = {};
    for (int c = 0; c < njc; ++c) {
        u16x8 vv = *(const u16x8*)(partial + (size_t)c * S_ * D_ + base);
#pragma unroll
        for (int e = 0; e < 8; ++e) s[e] += bf2f(vv[e]);
    }
    u16x8 o;
#pragma unroll
    for (int e = 0; e < 8; ++e) o[e] = f2bf(s[e]);
    *(u16x8*)(outp + base) = o;
}

extern "C" void kernel_launch(void* const* d_in, const int* in_sizes, int n_in,
                              void* d_out, int out_size, void* d_ws, size_t ws_size,
                              hipStream_t stream) {
    const float* q  = (const float*)d_in[0];
    const float* k  = (const float*)d_in[1];
    const float* v  = (const float*)d_in[2];
    const float* Wq = (const float*)d_in[3];
    const float* Wk = (const float*)d_in[4];
    const float* Wv = (const float*)d_in[5];
    const float* Wo = (const float*)d_in[6];

    // ws: 12MB (Qp,Kp,VpT) + njc*4MB (bf16 partial) + 4MB (ao)
    int njc = 2;
    if      (ws_size >= ((size_t)(16 + 4 * 8) << 20)) njc = 8;   // XCD == j-chunk
    else if (ws_size >= ((size_t)(16 + 4 * 4) << 20)) njc = 4;

    char* ws = (char*)d_ws;
    unsigned short* Qp  = (unsigned short*)(ws);                    // 4 MB bf16 [S][D]
    unsigned short* Kp  = (unsigned short*)(ws + (4u  << 20));      // 4 MB bf16 [S][D]
    unsigned short* VpT = (unsigned short*)(ws + (8u  << 20));      // 4 MB bf16 [D][S]
    unsigned short* part= (unsigned short*)(ws + (12u << 20));      // njc * 4 MB bf16 [jc][S][D]
    unsigned short* ao  = (unsigned short*)(ws + ((size_t)(12 + 4 * njc) << 20)); // 4 MB bf16

    const float qscale = 0.125f * 1.44269504088896340736f;  // 1/8 * log2(e)

    dim3 pb(256);
    dim3 pg(S_ / 128, D_ / 64);
    proj_kernel<false, 0><<<pg, pb, 0, stream>>>(q, Wq, Qp, qscale);
    proj_kernel<false, 0><<<pg, pb, 0, stream>>>(k, Wk, Kp, 1.0f);
    proj_kernel<false, 1><<<pg, pb, 0, stream>>>(v, Wv, VpT, 1.0f);
    attn_kernel<<<dim3(128 * njc), pb, 0, stream>>>(Qp, Kp, VpT, part, njc);
    reduceN_kernel<<<dim3(S_ * D_ / 2048), pb, 0, stream>>>(part, ao, njc);
    proj_kernel<true, 2><<<pg, pb, 0, stream>>>(ao, Wo, (float*)d_out, 1.0f);
}